// Round 2
// baseline (1557.530 us; speedup 1.0000x reference)
//
#include <hip/hip_runtime.h>
#include <math.h>

#define NTOK 32768
#define DDIM 768
#define HDIM 3072
#define NEXP 8
#define CAP  10240

typedef short short8 __attribute__((ext_vector_type(8)));
typedef float f32x4 __attribute__((ext_vector_type(4)));

__device__ __forceinline__ unsigned short f2bf(float f) {
  unsigned u = __float_as_uint(f);
  u += 0x7FFFu + ((u >> 16) & 1u);   // round-to-nearest-even (finite inputs)
  return (unsigned short)(u >> 16);
}
__device__ __forceinline__ float bf2f(unsigned short h) {
  return __uint_as_float((unsigned)h << 16);
}

__device__ __forceinline__ void gload16(const void* g, void* l) {
  __builtin_amdgcn_global_load_lds(
      (const __attribute__((address_space(1))) void*)g,
      (__attribute__((address_space(3))) void*)l, 16, 0, 0);
}

// ---------------------------------------------------------------------------
// Router phase 1: per-token top-2 + softmax -> pair/pw. Also x -> bf16.
// NO atomics.
// ---------------------------------------------------------------------------
__global__ __launch_bounds__(256) void router_assign(
    const float* __restrict__ x, const float* __restrict__ wg,
    unsigned short* __restrict__ xb,
    unsigned int* __restrict__ pair, float* __restrict__ pw)
{
  __shared__ float wt[NEXP][DDIM];       // transposed gate, 24 KB
  int t = threadIdx.x;
  for (int idx = t; idx < NEXP * DDIM; idx += 256) {
    int d = idx >> 3, e = idx & 7;       // wg is [768][8] row-major
    wt[e][d] = wg[idx];
  }
  __syncthreads();
  int wave = t >> 6, lane = t & 63;
  int n0 = blockIdx.x * 32 + wave * 8;
  for (int i = 0; i < 8; ++i) {
    int n = n0 + i;
    const float* xr = x + (size_t)n * DDIM;
    unsigned short* xbr = xb + (size_t)n * DDIM;
    float acc[NEXP];
#pragma unroll
    for (int e = 0; e < NEXP; ++e) acc[e] = 0.f;
#pragma unroll
    for (int c = 0; c < 3; ++c) {
      int d = c * 256 + lane * 4;
      float4 xv = *(const float4*)(xr + d);
      ushort4 pk;
      pk.x = f2bf(xv.x); pk.y = f2bf(xv.y); pk.z = f2bf(xv.z); pk.w = f2bf(xv.w);
      *(ushort4*)(xbr + d) = pk;
#pragma unroll
      for (int e = 0; e < NEXP; ++e) {
        float4 wv = *(const float4*)(&wt[e][d]);
        acc[e] += xv.x * wv.x + xv.y * wv.y + xv.z * wv.z + xv.w * wv.w;
      }
    }
#pragma unroll
    for (int e = 0; e < NEXP; ++e) {
      float v = acc[e];
      for (int o = 32; o > 0; o >>= 1) v += __shfl_xor(v, o, 64);
      acc[e] = v;
    }
    if (lane == 0) {
      int e1 = 0; float l1 = acc[0];
#pragma unroll
      for (int e = 1; e < NEXP; ++e) if (acc[e] > l1) { l1 = acc[e]; e1 = e; }
      int e2 = -1; float l2 = -INFINITY;
#pragma unroll
      for (int e = 0; e < NEXP; ++e) if (e != e1 && acc[e] > l2) { l2 = acc[e]; e2 = e; }
      float p1 = 1.f / (1.f + expf(l2 - l1));   // stable 2-way softmax
      pair[n] = (unsigned)e1 | ((unsigned)e2 << 8);
      pw[n] = p1;
    }
  }
}

// ---------------------------------------------------------------------------
// Router phase 2: one block per expert; compact token list in token order via
// ballot prefix-scan. NO global atomics. Also records per-token slot indices.
// ---------------------------------------------------------------------------
__global__ __launch_bounds__(256) void router_scatter(
    const unsigned int* __restrict__ pair, int* __restrict__ cnt,
    int* __restrict__ tokidx, int* __restrict__ slotof)
{
  int e = blockIdx.x;
  __shared__ int wsum[4];
  __shared__ int basev;
  int t = threadIdx.x, wave = t >> 6, lane = t & 63;
  if (t == 0) basev = 0;
  __syncthreads();
  for (int nb = 0; nb < NTOK; nb += 256) {
    int n = nb + t;
    unsigned p = pair[n];
    int e1 = p & 255, e2 = (p >> 8) & 255;
    bool m2 = (e2 == e);
    bool m = (e1 == e) | m2;
    unsigned long long bal = __ballot(m);
    int pre = __popcll(bal & ((1ull << lane) - 1ull));
    if (lane == 0) wsum[wave] = __popcll(bal);
    __syncthreads();
    int woff = 0;
    for (int wv = 0; wv < wave; ++wv) woff += wsum[wv];
    int tot = wsum[0] + wsum[1] + wsum[2] + wsum[3];
    int pos = basev + woff + pre;
    if (m) {
      if (pos < CAP) {
        tokidx[e * CAP + pos] = n;
        slotof[2 * n + (m2 ? 1 : 0)] = e * CAP + pos;
      } else {
        slotof[2 * n + (m2 ? 1 : 0)] = -1;   // dropped (never in practice)
      }
    }
    __syncthreads();
    if (t == 0) basev += tot;
  }
  __syncthreads();
  if (t == 0) cnt[e] = (basev < CAP) ? basev : CAP;
}

// ---------------------------------------------------------------------------
// Per-expert transpose + fp32->bf16: src [E][R][C] -> dst [E][C][R]
// ---------------------------------------------------------------------------
__global__ __launch_bounds__(256) void transpose_kernel(
    const float* __restrict__ src, unsigned short* __restrict__ dst, int R, int C)
{
  __shared__ float tile[64][65];
  int eb = blockIdx.z;
  const float* s = src + (size_t)eb * R * C;
  unsigned short* d = dst + (size_t)eb * R * C;
  int c0 = blockIdx.x * 64, r0 = blockIdx.y * 64;
  int tc = threadIdx.x & 63, tg = threadIdx.x >> 6;
#pragma unroll
  for (int rr = tg; rr < 64; rr += 4)
    tile[rr][tc] = s[(size_t)(r0 + rr) * C + c0 + tc];
  __syncthreads();
#pragma unroll
  for (int rr = tg; rr < 64; rr += 4)
    d[(size_t)(c0 + rr) * R + r0 + tc] = f2bf(tile[tc][rr]);
}

// ---------------------------------------------------------------------------
// Grouped GEMM, 256x256-tile 8-phase schedule (HK-style, plain HIP).
// BK=64 (two K-halves of 32), 512 threads = 8 waves (2M x 4N), per-wave
// output 128x64, mfma_f32_16x16x32_bf16. 128 KiB LDS: 2 buffers x
// (A 32KB + B 32KB), each operand split in K-halves of 16KB.
//
// Main loop (all stages unconditional; final iteration PEELED into a tail
// that stages only buf1.kh1 and drains vmcnt(0) once at ph3):
//   ph0: rd B,A(b0,ks0,mh0)  stage b1.A-kh1<-kt+1
//   ph1: rd A(b0,ks0,mh1)    stage b1.B-kh1<-kt+1
//   ph2: rd B,A(b0,ks1,mh0)  stage b0.A-kh0<-kt+2
//   ph3: rd A(b0,ks1,mh1)    stage b0.B-kh0<-kt+2   vmcnt(4) pre-barrier
//   ph4: rd B,A(b1,ks0,mh0)  stage b0.A-kh1<-kt+2
//   ph5: rd A(b1,ks0,mh1)    stage b0.B-kh1<-kt+2
//   ph6: rd B,A(b1,ks1,mh0)  stage b1.A-kh0<-kt+3
//   ph7: rd A(b1,ks1,mh1)    stage b1.B-kh0<-kt+3   vmcnt(4) pre-barrier
// Steady state: exactly 4 loads in flight after each vmcnt(4); every LDS
// slot's writer is issued after the barrier closing its last reader's phase.
//
// T2 swizzle: within a K-half (4 x 16B chunks/row), chunk ^= (row>>1)&3,
// applied on the pre-swizzled GLOBAL source (LDS dest stays linear for
// global_load_lds) and the same XOR on the ds_read side. Per quarter-wave
// (16 lanes x 16B) every bank is hit exactly 2x -> minimum aliasing (free).
//
// EPI=0: Obuf[e*Mc + row] = gelu(gather(xb) @ w1bt^T + b1)        (bf16)
// EPI=1: Obuf[e*CAP + gm] = Hbuf @ w2bt^T + b2  (bf16, un-weighted)
// ---------------------------------------------------------------------------
template<int EPI, int KK, int NN>
__global__ __launch_bounds__(512, 2) void moe_gemm(
    const unsigned short* __restrict__ A,
    const unsigned short* __restrict__ Bt,
    const float* __restrict__ bias,
    const int* __restrict__ cnt,
    const int* __restrict__ tokidx,
    unsigned short* __restrict__ Obuf,
    int mbase, int Mc)
{
  constexpr int KT = KK / 64;     // K-tiles of 64
  constexpr int NI = KT / 2;      // 2 K-tiles per iteration (NI >= 2)
  int e = blockIdx.z;
  int M = cnt[e]; if (M > CAP) M = CAP;
  int ly0 = blockIdx.y * 256;           // local row base within chunk
  int gm0 = mbase + ly0;                // global slot base
  if (gm0 >= M) return;
  int n0 = blockIdx.x * 256;
  int t = threadIdx.x, wave = t >> 6, lane = t & 63;
  int wr = wave >> 2, wc = wave & 3;    // 2M x 4N wave grid
  int lane15 = lane & 15, quad = lane >> 4;

  __shared__ __align__(16) char smem[131072];

  // ---- staging: each thread owns 2 of the 1024 16B-chunks per half-tile ----
  int ci0 = wave * 128 + lane;
  int ci1 = ci0 + 64;
  int r0 = ci0 >> 2, r1 = ci1 >> 2;     // tile row 0..255
  int c0 = (ci0 & 3) ^ ((r0 >> 1) & 3); // pre-swizzled source chunk in K-half
  int c1 = (ci1 & 3) ^ ((r1 >> 1) & 3);
  const unsigned short *aB0, *aB1, *bB0, *bB1;
  if (EPI == 0) {
    int g0 = gm0 + r0; if (g0 >= M) g0 = M - 1;   // clamp to a valid slot
    int g1 = gm0 + r1; if (g1 >= M) g1 = M - 1;
    aB0 = A + (size_t)tokidx[e * CAP + g0] * KK + c0 * 8;
    aB1 = A + (size_t)tokidx[e * CAP + g1] * KK + c1 * 8;
  } else {
    aB0 = A + ((size_t)e * Mc + ly0 + r0) * KK + c0 * 8;
    aB1 = A + ((size_t)e * Mc + ly0 + r1) * KK + c1 * 8;
  }
  bB0 = Bt + ((size_t)e * NN + n0 + r0) * KK + c0 * 8;
  bB1 = Bt + ((size_t)e * NN + n0 + r1) * KK + c1 * 8;

  // dest: smem + buf*65536 + ab*32768 + kh*16384 + wave*2048 (+1024), +lane*16 by HW
#define STAGE_A(buf, kh, kt_) do { \
    gload16(aB0 + (kt_) * 64 + (kh) * 32, smem + (buf) * 65536 + (kh) * 16384 + wave * 2048); \
    gload16(aB1 + (kt_) * 64 + (kh) * 32, smem + (buf) * 65536 + (kh) * 16384 + wave * 2048 + 1024); \
  } while (0)
#define STAGE_B(buf, kh, kt_) do { \
    gload16(bB0 + (kt_) * 64 + (kh) * 32, smem + (buf) * 65536 + 32768 + (kh) * 16384 + wave * 2048); \
    gload16(bB1 + (kt_) * 64 + (kh) * 32, smem + (buf) * 65536 + 32768 + (kh) * 16384 + wave * 2048 + 1024); \
  } while (0)

  // ---- ds_read fragment offsets (swizzled) ----
  int aoffb[8], boffb[4];
#pragma unroll
  for (int m = 0; m < 8; ++m) {
    int row = wr * 128 + m * 16 + lane15;
    aoffb[m] = row * 64 + ((quad ^ ((row >> 1) & 3)) * 16);
  }
#pragma unroll
  for (int n = 0; n < 4; ++n) {
    int row = wc * 64 + n * 16 + lane15;
    boffb[n] = 32768 + row * 64 + ((quad ^ ((row >> 1) & 3)) * 16);
  }

  f32x4 acc[8][4];
#pragma unroll
  for (int mf = 0; mf < 8; ++mf)
#pragma unroll
    for (int n = 0; n < 4; ++n)
#pragma unroll
      for (int r = 0; r < 4; ++r) acc[mf][n][r] = 0.f;

  short8 af[4], bf[4];

#define BAR()  __builtin_amdgcn_s_barrier()
#define WVM4() asm volatile("s_waitcnt vmcnt(4)" ::: "memory")
#define WVM0() asm volatile("s_waitcnt vmcnt(0)" ::: "memory")
#define RD_B(buf, ks) do { \
    _Pragma("unroll") \
    for (int n = 0; n < 4; ++n) \
      bf[n] = *(const short8*)(smem + (buf) * 65536 + (ks) * 16384 + boffb[n]); \
  } while (0)
#define RD_A(buf, ks, mh) do { \
    _Pragma("unroll") \
    for (int m = 0; m < 4; ++m) \
      af[m] = *(const short8*)(smem + (buf) * 65536 + (ks) * 16384 + aoffb[(mh) * 4 + m]); \
  } while (0)
#define MM(mh) do { \
    __builtin_amdgcn_s_setprio(1); \
    _Pragma("unroll") \
    for (int m = 0; m < 4; ++m) \
      _Pragma("unroll") \
      for (int n = 0; n < 4; ++n) \
        acc[(mh) * 4 + m][n] = __builtin_amdgcn_mfma_f32_16x16x32_bf16( \
            af[m], bf[n], acc[(mh) * 4 + m][n], 0, 0, 0); \
    __builtin_amdgcn_s_setprio(0); \
  } while (0)

  // ---- prologue: buf0 <- tile0 (all 4 halves), buf1.kh0 <- tile1 ----
  STAGE_A(0, 0, 0); STAGE_B(0, 0, 0);
  STAGE_A(0, 1, 0); STAGE_B(0, 1, 0);
  STAGE_A(1, 0, 1); STAGE_B(1, 0, 1);
  WVM4();                // buf0 fully landed; buf1.kh0 (4 loads) may fly
  BAR();

#pragma unroll 1
  for (int it = 0; it < NI - 1; ++it) {
    int kt = 2 * it;
    // ph0
    RD_B(0, 0); RD_A(0, 0, 0); STAGE_A(1, 1, kt + 1);
    BAR(); MM(0); BAR();
    // ph1
    RD_A(0, 0, 1); STAGE_B(1, 1, kt + 1);
    BAR(); MM(1); BAR();
    // ph2
    RD_B(0, 1); RD_A(0, 1, 0); STAGE_A(0, 0, kt + 2);
    BAR(); MM(0); BAR();
    // ph3
    RD_A(0, 1, 1); STAGE_B(0, 0, kt + 2);
    BAR(); MM(1); WVM4(); BAR();     // buf1.kh0/kh1 landed for ph4..ph7
    // ph4
    RD_B(1, 0); RD_A(1, 0, 0); STAGE_A(0, 1, kt + 2);
    BAR(); MM(0); BAR();
    // ph5
    RD_A(1, 0, 1); STAGE_B(0, 1, kt + 2);
    BAR(); MM(1); BAR();
    // ph6
    RD_B(1, 1); RD_A(1, 1, 0); STAGE_A(1, 0, kt + 3);
    BAR(); MM(0); BAR();
    // ph7
    RD_A(1, 1, 1); STAGE_B(1, 0, kt + 3);
    BAR(); MM(1); WVM4(); BAR();     // next iter's buf0 landed
  }

  // ---- peeled tail (tiles KT-2 / KT-1): stage only buf1.kh1, drain once ----
  {
    constexpr int kt = 2 * (NI - 1);
    RD_B(0, 0); RD_A(0, 0, 0); STAGE_A(1, 1, kt + 1);
    BAR(); MM(0); BAR();
    RD_A(0, 0, 1); STAGE_B(1, 1, kt + 1);
    BAR(); MM(1); BAR();
    RD_B(0, 1); RD_A(0, 1, 0);
    BAR(); MM(0); BAR();
    RD_A(0, 1, 1);
    BAR(); MM(1); WVM0(); BAR();     // ALL of buf1 landed (incl. kh1 just staged)
    RD_B(1, 0); RD_A(1, 0, 0);
    BAR(); MM(0); BAR();
    RD_A(1, 0, 1);
    BAR(); MM(1); BAR();
    RD_B(1, 1); RD_A(1, 1, 0);
    BAR(); MM(0); BAR();
    RD_A(1, 1, 1);
    BAR(); MM(1);
  }

  // epilogue: C/D layout col=lane&15, row=quad*4+reg  [m89-verified]
  if (EPI == 0) {
#pragma unroll
    for (int n = 0; n < 4; ++n) {
      int col = n0 + wc * 64 + n * 16 + lane15;
      float bcol = bias[e * NN + col];
#pragma unroll
      for (int mf = 0; mf < 8; ++mf) {
        int rowb = ly0 + wr * 128 + mf * 16 + quad * 4;   // local row
#pragma unroll
        for (int r = 0; r < 4; ++r) {
          float v = acc[mf][n][r] + bcol;
          v = 0.5f * v * (1.f + erff(v * 0.70710678118654752f));  // exact GELU
          Obuf[((size_t)e * Mc + rowb + r) * NN + col] = f2bf(v);
        }
      }
    }
  } else {
    float bc[4];
#pragma unroll
    for (int n = 0; n < 4; ++n)
      bc[n] = bias[e * NN + n0 + wc * 64 + n * 16 + lane15];
#pragma unroll
    for (int mf = 0; mf < 8; ++mf) {
      int gmb = gm0 + wr * 128 + mf * 16 + quad * 4;      // global slot
#pragma unroll
      for (int r = 0; r < 4; ++r) {
        int gm = gmb + r;
        if (gm < M) {
          unsigned short* yrow = Obuf + ((size_t)e * CAP + gm) * NN;
#pragma unroll
          for (int n = 0; n < 4; ++n) {
            int col = n0 + wc * 64 + n * 16 + lane15;
            yrow[col] = f2bf(acc[mf][n][r] + bc[n]);
          }
        }
      }
    }
  }
#undef STAGE_A
#undef STAGE_B
#undef BAR
#undef WVM4
#undef WVM0
#undef RD_B
#undef RD_A
#undef MM
}

// ---------------------------------------------------------------------------
// Fused combine (weighted sum of the token's two expert outputs) + LayerNorm.
// ---------------------------------------------------------------------------
__global__ __launch_bounds__(256) void combine_ln(
    const unsigned short* __restrict__ Y, const int* __restrict__ slotof,
    const float* __restrict__ pw,
    const float* __restrict__ lnw, const float* __restrict__ lnb,
    float* __restrict__ out)
{
  __shared__ float red[8];
  int n = blockIdx.x;
  int s0 = slotof[2 * n], s1 = slotof[2 * n + 1];
  float p0 = pw[n], p1 = 1.f - p0;
  const unsigned short* y0 = Y + (size_t)(s0 < 0 ? 0 : s0) * DDIM;
  const unsigned short* y1 = Y + (size_t)(s1 < 0 ? 0 : s1) * DDIM;
  if (s0 < 0) p0 = 0.f;
  if (s1 < 0) p1 = 0.f;
  int t = threadIdx.x;
  float v0 = p0 * bf2f(y0[t])       + p1 * bf2f(y1[t]);
  float v1 = p0 * bf2f(y0[t + 256]) + p1 * bf2f(y1[t + 256]);
  float v2 = p0 * bf2f(y0[t + 512]) + p1 * bf2f(y1[t + 512]);
  float s = v0 + v1 + v2;
  float ss = v0 * v0 + v1 * v1 + v2 * v2;
  for (int o = 32; o > 0; o >>= 1) { s += __shfl_xor(s, o, 64); ss += __shfl_xor(ss, o, 64); }
  int wave = t >> 6, lane = t & 63;
  if (lane == 0) { red[wave] = s; red[4 + wave] = ss; }
  __syncthreads();
  s = red[0] + red[1] + red[2] + red[3];
  ss = red[4] + red[5] + red[6] + red[7];
  float mu = s * (1.f / DDIM);
  float var = ss * (1.f / DDIM) - mu * mu;
  float rs = rsqrtf(var + 1e-5f);
  float* row = out + (size_t)n * DDIM;
  row[t]       = (v0 - mu) * rs * lnw[t]       + lnb[t];
  row[t + 256] = (v1 - mu) * rs * lnw[t + 256] + lnb[t + 256];
  row[t + 512] = (v2 - mu) * rs * lnw[t + 512] + lnb[t + 512];
}

// sentinel fill: signals "workspace too small" via a distinctive absmax
__global__ void sentinel_kernel(float* __restrict__ out, int n) {
  int i = blockIdx.x * 256 + threadIdx.x;
  if (i < n) out[i] = 12345.0f;
}

// ---------------------------------------------------------------------------
extern "C" void kernel_launch(void* const* d_in, const int* in_sizes, int n_in,
                              void* d_out, int out_size, void* d_ws, size_t ws_size,
                              hipStream_t stream)
{
  const float* x   = (const float*)d_in[0];
  const float* wg  = (const float*)d_in[1];
  const float* w1  = (const float*)d_in[2];
  const float* b1  = (const float*)d_in[3];
  const float* w2  = (const float*)d_in[4];
  const float* b2  = (const float*)d_in[5];
  const float* lnw = (const float*)d_in[6];
  const float* lnb = (const float*)d_in[7];
  float* out = (float*)d_out;

  char* ws = (char*)d_ws;
  size_t off = 0;
  auto take = [&](size_t bytes) {
    char* p = ws + off; off += (bytes + 255) & ~(size_t)255; return p;
  };
  unsigned short* xb   = (unsigned short*)take((size_t)NTOK * DDIM * 2);        // 50.3 MB
  unsigned short* w1bt = (unsigned short*)take((size_t)NEXP * DDIM * HDIM * 2); // 37.7 MB
  unsigned short* w2bt = (unsigned short*)take((size_t)NEXP * DDIM * HDIM * 2); // 37.7 MB
  int*   tokidx = (int*)take((size_t)NEXP * CAP * 4);
  unsigned int* pair = (unsigned int*)take((size_t)NTOK * 4);
  float* pw   = (float*)take((size_t)NTOK * 4);
  int*   slotof = (int*)take((size_t)NTOK * 2 * 4);
  int*   cnt  = (int*)take(256);
  unsigned short* Ybuf = (unsigned short*)take((size_t)NEXP * CAP * DDIM * 2);  // 125.8 MB

  // Adaptive H-chunk: Mc token rows per expert (multiple of 256 for the
  // 256-row GEMM tiles), bounded by remaining workspace.
  size_t avail = (ws_size > off) ? (ws_size - off) : 0;
  long long cand = (long long)(avail / ((size_t)NEXP * HDIM * 2));  // rows/expert
  int Mc = (int)((cand / 256) * 256);
  if (Mc > CAP) Mc = CAP;
  if (Mc < 256) {   // cannot run at all — emit sentinel instead of crashing
    sentinel_kernel<<<(NTOK * DDIM + 255) / 256, 256, 0, stream>>>(out, NTOK * DDIM);
    return;
  }
  unsigned short* Hbuf = (unsigned short*)take((size_t)NEXP * Mc * HDIM * 2);

  router_assign<<<NTOK / 32, 256, 0, stream>>>(x, wg, xb, pair, pw);
  transpose_kernel<<<dim3(HDIM / 64, DDIM / 64, NEXP), 256, 0, stream>>>(w1, w1bt, DDIM, HDIM);
  transpose_kernel<<<dim3(DDIM / 64, HDIM / 64, NEXP), 256, 0, stream>>>(w2, w2bt, HDIM, DDIM);
  router_scatter<<<NEXP, 256, 0, stream>>>(pair, cnt, tokidx, slotof);

  for (int mbase = 0; mbase < CAP; mbase += Mc) {
    int rows = CAP - mbase; if (rows > Mc) rows = Mc;
    int mt = rows / 256;
    moe_gemm<0, DDIM, HDIM><<<dim3(HDIM / 256, mt, NEXP), 512, 0, stream>>>(
        xb, w1bt, b1, cnt, tokidx, Hbuf, mbase, Mc);
    moe_gemm<1, HDIM, DDIM><<<dim3(DDIM / 256, mt, NEXP), 512, 0, stream>>>(
        Hbuf, w2bt, b2, cnt, tokidx, Ybuf, mbase, Mc);
  }

  combine_ln<<<NTOK, 256, 0, stream>>>(Ybuf, slotof, pw, lnw, lnb, out);
}

// Round 3
// 1513.767 us; speedup vs baseline: 1.0289x; 1.0289x over previous
//
#include <hip/hip_runtime.h>
#include <math.h>

#define NTOK 32768
#define DDIM 768
#define HDIM 3072
#define NEXP 8
#define CAP  10240

typedef short short8 __attribute__((ext_vector_type(8)));
typedef float f32x4 __attribute__((ext_vector_type(4)));

__device__ __forceinline__ unsigned short f2bf(float f) {
  unsigned u = __float_as_uint(f);
  u += 0x7FFFu + ((u >> 16) & 1u);   // round-to-nearest-even (finite inputs)
  return (unsigned short)(u >> 16);
}
__device__ __forceinline__ float bf2f(unsigned short h) {
  return __uint_as_float((unsigned)h << 16);
}

__device__ __forceinline__ void gload16(const void* g, void* l) {
  __builtin_amdgcn_global_load_lds(
      (const __attribute__((address_space(1))) void*)g,
      (__attribute__((address_space(3))) void*)l, 16, 0, 0);
}

// Fast exact-GELU: 0.5*v*(1+erf(v/sqrt2)), erf via A&S 7.1.26 (|err|<1.5e-7).
// Output is stored to bf16 (rel quantum ~4e-3) -> approximation error invisible.
__device__ __forceinline__ float gelu_fast(float v) {
  float z = v * 0.70710678118654752f;
  float a = fabsf(z);
  float t = 1.0f / (1.0f + 0.3275911f * a);
  float p = t * (0.254829592f +
           t * (-0.284496736f +
           t * (1.421413741f +
           t * (-1.453152027f +
           t * 1.061405429f))));
  float ex = __expf(-a * a);
  float er = 1.0f - p * ex;              // er in [0,1]
  er = copysignf(er, z);
  return 0.5f * v * (1.0f + er);
}

// ---------------------------------------------------------------------------
// Router phase 1: per-token top-2 + softmax -> pair/pw. Also x -> bf16.
// ---------------------------------------------------------------------------
__global__ __launch_bounds__(256) void router_assign(
    const float* __restrict__ x, const float* __restrict__ wg,
    unsigned short* __restrict__ xb,
    unsigned int* __restrict__ pair, float* __restrict__ pw)
{
  __shared__ float wt[NEXP][DDIM];       // transposed gate, 24 KB
  int t = threadIdx.x;
  for (int idx = t; idx < NEXP * DDIM; idx += 256) {
    int d = idx >> 3, e = idx & 7;       // wg is [768][8] row-major
    wt[e][d] = wg[idx];
  }
  __syncthreads();
  int wave = t >> 6, lane = t & 63;
  int n0 = blockIdx.x * 32 + wave * 8;
  for (int i = 0; i < 8; ++i) {
    int n = n0 + i;
    const float* xr = x + (size_t)n * DDIM;
    unsigned short* xbr = xb + (size_t)n * DDIM;
    float acc[NEXP];
#pragma unroll
    for (int e = 0; e < NEXP; ++e) acc[e] = 0.f;
#pragma unroll
    for (int c = 0; c < 3; ++c) {
      int d = c * 256 + lane * 4;
      float4 xv = *(const float4*)(xr + d);
      ushort4 pk;
      pk.x = f2bf(xv.x); pk.y = f2bf(xv.y); pk.z = f2bf(xv.z); pk.w = f2bf(xv.w);
      *(ushort4*)(xbr + d) = pk;
#pragma unroll
      for (int e = 0; e < NEXP; ++e) {
        float4 wv = *(const float4*)(&wt[e][d]);
        acc[e] += xv.x * wv.x + xv.y * wv.y + xv.z * wv.z + xv.w * wv.w;
      }
    }
#pragma unroll
    for (int e = 0; e < NEXP; ++e) {
      float v = acc[e];
      for (int o = 32; o > 0; o >>= 1) v += __shfl_xor(v, o, 64);
      acc[e] = v;
    }
    if (lane == 0) {
      int e1 = 0; float l1 = acc[0];
#pragma unroll
      for (int e = 1; e < NEXP; ++e) if (acc[e] > l1) { l1 = acc[e]; e1 = e; }
      int e2 = -1; float l2 = -INFINITY;
#pragma unroll
      for (int e = 0; e < NEXP; ++e) if (e != e1 && acc[e] > l2) { l2 = acc[e]; e2 = e; }
      float p1 = 1.f / (1.f + expf(l2 - l1));   // stable 2-way softmax
      pair[n] = (unsigned)e1 | ((unsigned)e2 << 8);
      pw[n] = p1;
    }
  }
}

// ---------------------------------------------------------------------------
// Router phase 2: one block per expert; compact token list in token order via
// ballot prefix-scan. NO global atomics. Also records per-token slot indices.
// ---------------------------------------------------------------------------
__global__ __launch_bounds__(256) void router_scatter(
    const unsigned int* __restrict__ pair, int* __restrict__ cnt,
    int* __restrict__ tokidx, int* __restrict__ slotof)
{
  int e = blockIdx.x;
  __shared__ int wsum[4];
  __shared__ int basev;
  int t = threadIdx.x, wave = t >> 6, lane = t & 63;
  if (t == 0) basev = 0;
  __syncthreads();
  for (int nb = 0; nb < NTOK; nb += 256) {
    int n = nb + t;
    unsigned p = pair[n];
    int e1 = p & 255, e2 = (p >> 8) & 255;
    bool m2 = (e2 == e);
    bool m = (e1 == e) | m2;
    unsigned long long bal = __ballot(m);
    int pre = __popcll(bal & ((1ull << lane) - 1ull));
    if (lane == 0) wsum[wave] = __popcll(bal);
    __syncthreads();
    int woff = 0;
    for (int wv = 0; wv < wave; ++wv) woff += wsum[wv];
    int tot = wsum[0] + wsum[1] + wsum[2] + wsum[3];
    int pos = basev + woff + pre;
    if (m) {
      if (pos < CAP) {
        tokidx[e * CAP + pos] = n;
        slotof[2 * n + (m2 ? 1 : 0)] = e * CAP + pos;
      } else {
        slotof[2 * n + (m2 ? 1 : 0)] = -1;   // dropped (never in practice)
      }
    }
    __syncthreads();
    if (t == 0) basev += tot;
  }
  __syncthreads();
  if (t == 0) cnt[e] = (basev < CAP) ? basev : CAP;
}

// ---------------------------------------------------------------------------
// Per-expert transpose + fp32->bf16: src [E][R][C] -> dst [E][C][R]
// ---------------------------------------------------------------------------
__global__ __launch_bounds__(256) void transpose_kernel(
    const float* __restrict__ src, unsigned short* __restrict__ dst, int R, int C)
{
  __shared__ float tile[64][65];
  int eb = blockIdx.z;
  const float* s = src + (size_t)eb * R * C;
  unsigned short* d = dst + (size_t)eb * R * C;
  int c0 = blockIdx.x * 64, r0 = blockIdx.y * 64;
  int tc = threadIdx.x & 63, tg = threadIdx.x >> 6;
#pragma unroll
  for (int rr = tg; rr < 64; rr += 4)
    tile[rr][tc] = s[(size_t)(r0 + rr) * C + c0 + tc];
  __syncthreads();
#pragma unroll
  for (int rr = tg; rr < 64; rr += 4)
    d[(size_t)(c0 + rr) * R + r0 + tc] = f2bf(tile[tc][rr]);
}

// ---------------------------------------------------------------------------
// Grouped GEMM, 256x256-tile 8-phase schedule. BK=64 (two K-halves of 32),
// 512 threads = 8 waves (2M x 4N), per-wave output 128x64,
// mfma_f32_16x16x32_bf16. 128 KiB LDS: 2 buffers x (A 32KB + B 32KB),
// each operand split in K-halves of 16KB.
//
// Staging positions (unchanged from r1, write-after-read safe):
//   ph0: rd B,A(b0,ks0,mh0)  stage b1.A-kh1<-kt+1
//   ph1: rd A(b0,ks0,mh1)    stage b1.B-kh1<-kt+1   vmcnt(8)
//   ph2: rd B,A(b0,ks1,mh0)  stage b0.A-kh0<-kt+2
//   ph3: rd A(b0,ks1,mh1)    stage b0.B-kh0<-kt+2   vmcnt(8)
//   ph4: rd B,A(b1,ks0,mh0)  stage b0.A-kh1<-kt+2
//   ph5: rd A(b1,ks0,mh1)    stage b0.B-kh1<-kt+2   vmcnt(8)
//   ph6: rd B,A(b1,ks1,mh0)  stage b1.A-kh0<-kt+3
//   ph7: rd A(b1,ks1,mh1)    stage b1.B-kh0<-kt+3   vmcnt(8)
// vmcnt(8) at EVERY odd phase = 4 half-tiles in flight; each wait completes
// exactly the half-tile the next phase reads, staged 4-5 phases (~700-900cy)
// earlier -> HBM latency covered. Tail peels with vmcnt 8 -> 4 -> 0.
//
// T2 swizzle: within a K-half (4 x 16B chunks/row), chunk ^= (row>>1)&3,
// pre-swizzled on the GLOBAL source (LDS dest linear for global_load_lds),
// same XOR on ds_read. Conflict-free (measured: SQ_LDS_BANK_CONFLICT=0).
//
// T1: bijective XCD-chunked swizzle of the flattened 1D grid (m204 formula).
//
// EPI=0: Obuf[e*Mc + row] = gelu(gather(xb) @ w1bt^T + b1)        (bf16)
// EPI=1: Obuf[e*CAP + gm] = Hbuf @ w2bt^T + b2  (bf16, un-weighted)
// ---------------------------------------------------------------------------
template<int EPI, int KK, int NN>
__global__ __launch_bounds__(512, 2) void moe_gemm(
    const unsigned short* __restrict__ A,
    const unsigned short* __restrict__ Bt,
    const float* __restrict__ bias,
    const int* __restrict__ cnt,
    const int* __restrict__ tokidx,
    unsigned short* __restrict__ Obuf,
    int mbase, int Mc, int mt)
{
  constexpr int KT = KK / 64;     // K-tiles of 64
  constexpr int NI = KT / 2;      // 2 K-tiles per iteration (NI >= 2)
  constexpr int GX = NN / 256;    // N-tiles (compile-time)

  // ---- T1: bijective XCD-chunk remap of flattened block id ----
  int nwg = gridDim.x;
  int orig = blockIdx.x;
  int q = nwg >> 3, r = nwg & 7;
  int xcd = orig & 7, loc = orig >> 3;
  int base = (xcd < r) ? xcd * (q + 1) : r * (q + 1) + (xcd - r) * q;
  int wg = base + loc;
  int per_e = GX * mt;
  int e = wg / per_e;
  int rem = wg - e * per_e;
  int by = rem / GX;
  int bx = rem - by * GX;

  int M = cnt[e]; if (M > CAP) M = CAP;
  int ly0 = by * 256;                   // local row base within chunk
  int gm0 = mbase + ly0;                // global slot base
  if (gm0 >= M) return;
  int n0 = bx * 256;
  int t = threadIdx.x, wave = t >> 6, lane = t & 63;
  int wr = wave >> 2, wc = wave & 3;    // 2M x 4N wave grid
  int lane15 = lane & 15, quad = lane >> 4;

  __shared__ __align__(16) char smem[131072];

  // ---- staging: each thread owns 2 of the 1024 16B-chunks per half-tile ----
  int ci0 = wave * 128 + lane;
  int ci1 = ci0 + 64;
  int r0 = ci0 >> 2, r1 = ci1 >> 2;     // tile row 0..255
  int c0 = (ci0 & 3) ^ ((r0 >> 1) & 3); // pre-swizzled source chunk in K-half
  int c1 = (ci1 & 3) ^ ((r1 >> 1) & 3);
  const unsigned short *aB0, *aB1, *bB0, *bB1;
  if (EPI == 0) {
    int g0 = gm0 + r0; if (g0 >= M) g0 = M - 1;   // clamp to a valid slot
    int g1 = gm0 + r1; if (g1 >= M) g1 = M - 1;
    aB0 = A + (size_t)tokidx[e * CAP + g0] * KK + c0 * 8;
    aB1 = A + (size_t)tokidx[e * CAP + g1] * KK + c1 * 8;
  } else {
    aB0 = A + ((size_t)e * Mc + ly0 + r0) * KK + c0 * 8;
    aB1 = A + ((size_t)e * Mc + ly0 + r1) * KK + c1 * 8;
  }
  bB0 = Bt + ((size_t)e * NN + n0 + r0) * KK + c0 * 8;
  bB1 = Bt + ((size_t)e * NN + n0 + r1) * KK + c1 * 8;

  // dest: smem + buf*65536 + ab*32768 + kh*16384 + wave*2048 (+1024), +lane*16 by HW
#define STAGE_A(buf, kh, kt_) do { \
    gload16(aB0 + (kt_) * 64 + (kh) * 32, smem + (buf) * 65536 + (kh) * 16384 + wave * 2048); \
    gload16(aB1 + (kt_) * 64 + (kh) * 32, smem + (buf) * 65536 + (kh) * 16384 + wave * 2048 + 1024); \
  } while (0)
#define STAGE_B(buf, kh, kt_) do { \
    gload16(bB0 + (kt_) * 64 + (kh) * 32, smem + (buf) * 65536 + 32768 + (kh) * 16384 + wave * 2048); \
    gload16(bB1 + (kt_) * 64 + (kh) * 32, smem + (buf) * 65536 + 32768 + (kh) * 16384 + wave * 2048 + 1024); \
  } while (0)

  // ---- ds_read fragment offsets (swizzled) ----
  int aoffb[8], boffb[4];
#pragma unroll
  for (int m = 0; m < 8; ++m) {
    int row = wr * 128 + m * 16 + lane15;
    aoffb[m] = row * 64 + ((quad ^ ((row >> 1) & 3)) * 16);
  }
#pragma unroll
  for (int n = 0; n < 4; ++n) {
    int row = wc * 64 + n * 16 + lane15;
    boffb[n] = 32768 + row * 64 + ((quad ^ ((row >> 1) & 3)) * 16);
  }

  f32x4 acc[8][4];
#pragma unroll
  for (int mf = 0; mf < 8; ++mf)
#pragma unroll
    for (int n = 0; n < 4; ++n)
#pragma unroll
      for (int r = 0; r < 4; ++r) acc[mf][n][r] = 0.f;

  short8 af[4], bf[4];

#define BAR()  __builtin_amdgcn_s_barrier()
#define WVM8() asm volatile("s_waitcnt vmcnt(8)" ::: "memory")
#define WVM4() asm volatile("s_waitcnt vmcnt(4)" ::: "memory")
#define WVM0() asm volatile("s_waitcnt vmcnt(0)" ::: "memory")
#define RD_B(buf, ks) do { \
    _Pragma("unroll") \
    for (int n = 0; n < 4; ++n) \
      bf[n] = *(const short8*)(smem + (buf) * 65536 + (ks) * 16384 + boffb[n]); \
  } while (0)
#define RD_A(buf, ks, mh) do { \
    _Pragma("unroll") \
    for (int m = 0; m < 4; ++m) \
      af[m] = *(const short8*)(smem + (buf) * 65536 + (ks) * 16384 + aoffb[(mh) * 4 + m]); \
  } while (0)
#define MM(mh) do { \
    __builtin_amdgcn_s_setprio(1); \
    _Pragma("unroll") \
    for (int m = 0; m < 4; ++m) \
      _Pragma("unroll") \
      for (int n = 0; n < 4; ++n) \
        acc[(mh) * 4 + m][n] = __builtin_amdgcn_mfma_f32_16x16x32_bf16( \
            af[m], bf[n], acc[(mh) * 4 + m][n], 0, 0, 0); \
    __builtin_amdgcn_s_setprio(0); \
  } while (0)

  // ---- prologue: buf0 <- tile0 (all 4 halves), buf1.kh0 <- tile1 ----
  STAGE_A(0, 0, 0); STAGE_B(0, 0, 0);
  STAGE_A(0, 1, 0); STAGE_B(0, 1, 0);
  STAGE_A(1, 0, 1); STAGE_B(1, 0, 1);
  WVM8();                // buf0.kh0 landed; 8 in flight (buf0.kh1, buf1.kh0)
  BAR();

#pragma unroll 1
  for (int it = 0; it < NI - 1; ++it) {
    int kt = 2 * it;
    // ph0
    RD_B(0, 0); RD_A(0, 0, 0); STAGE_A(1, 1, kt + 1);
    BAR(); MM(0); BAR();
    // ph1
    RD_A(0, 0, 1); STAGE_B(1, 1, kt + 1);
    BAR(); MM(1); WVM8(); BAR();     // buf0.kh1 landed (ph2 reads)
    // ph2
    RD_B(0, 1); RD_A(0, 1, 0); STAGE_A(0, 0, kt + 2);
    BAR(); MM(0); BAR();
    // ph3
    RD_A(0, 1, 1); STAGE_B(0, 0, kt + 2);
    BAR(); MM(1); WVM8(); BAR();     // buf1.kh0 landed (ph4 reads)
    // ph4
    RD_B(1, 0); RD_A(1, 0, 0); STAGE_A(0, 1, kt + 2);
    BAR(); MM(0); BAR();
    // ph5
    RD_A(1, 0, 1); STAGE_B(0, 1, kt + 2);
    BAR(); MM(1); WVM8(); BAR();     // buf1.kh1 landed (ph6 reads)
    // ph6
    RD_B(1, 1); RD_A(1, 1, 0); STAGE_A(1, 0, kt + 3);
    BAR(); MM(0); BAR();
    // ph7
    RD_A(1, 1, 1); STAGE_B(1, 0, kt + 3);
    BAR(); MM(1); WVM8(); BAR();     // buf0.kh0 landed (next ph0 reads)
  }

  // ---- peeled tail (tiles KT-2 / KT-1): stage only buf1.kh1; drain 8->4->0 ----
  {
    constexpr int kt = 2 * (NI - 1);
    RD_B(0, 0); RD_A(0, 0, 0); STAGE_A(1, 1, kt + 1);
    BAR(); MM(0); BAR();
    RD_A(0, 0, 1); STAGE_B(1, 1, kt + 1);
    BAR(); MM(1); WVM8(); BAR();     // buf0.kh1 landed
    RD_B(0, 1); RD_A(0, 1, 0);
    BAR(); MM(0); BAR();
    RD_A(0, 1, 1);
    BAR(); MM(1); WVM4(); BAR();     // buf1.kh0 landed
    RD_B(1, 0); RD_A(1, 0, 0);
    BAR(); MM(0); BAR();
    RD_A(1, 0, 1);
    BAR(); MM(1); WVM0(); BAR();     // buf1.kh1 landed
    RD_B(1, 1); RD_A(1, 1, 0);
    BAR(); MM(0); BAR();
    RD_A(1, 1, 1);
    BAR(); MM(1);
  }

  // epilogue: C/D layout col=lane&15, row=quad*4+reg  [m89-verified]
  if (EPI == 0) {
#pragma unroll
    for (int n = 0; n < 4; ++n) {
      int col = n0 + wc * 64 + n * 16 + lane15;
      float bcol = bias[e * NN + col];
#pragma unroll
      for (int mf = 0; mf < 8; ++mf) {
        int rowb = ly0 + wr * 128 + mf * 16 + quad * 4;   // local row
#pragma unroll
        for (int r = 0; r < 4; ++r) {
          float v = gelu_fast(acc[mf][n][r] + bcol);
          Obuf[((size_t)e * Mc + rowb + r) * NN + col] = f2bf(v);
        }
      }
    }
  } else {
    float bc[4];
#pragma unroll
    for (int n = 0; n < 4; ++n)
      bc[n] = bias[e * NN + n0 + wc * 64 + n * 16 + lane15];
#pragma unroll
    for (int mf = 0; mf < 8; ++mf) {
      int gmb = gm0 + wr * 128 + mf * 16 + quad * 4;      // global slot
#pragma unroll
      for (int r = 0; r < 4; ++r) {
        int gm = gmb + r;
        if (gm < M) {
          unsigned short* yrow = Obuf + ((size_t)e * CAP + gm) * NN;
#pragma unroll
          for (int n = 0; n < 4; ++n) {
            int col = n0 + wc * 64 + n * 16 + lane15;
            yrow[col] = f2bf(acc[mf][n][r] + bc[n]);
          }
        }
      }
    }
  }
#undef STAGE_A
#undef STAGE_B
#undef BAR
#undef WVM8
#undef WVM4
#undef WVM0
#undef RD_B
#undef RD_A
#undef MM
}

// ---------------------------------------------------------------------------
// Fused combine (weighted sum of the token's two expert outputs) + LayerNorm.
// ---------------------------------------------------------------------------
__global__ __launch_bounds__(256) void combine_ln(
    const unsigned short* __restrict__ Y, const int* __restrict__ slotof,
    const float* __restrict__ pw,
    const float* __restrict__ lnw, const float* __restrict__ lnb,
    float* __restrict__ out)
{
  __shared__ float red[8];
  int n = blockIdx.x;
  int s0 = slotof[2 * n], s1 = slotof[2 * n + 1];
  float p0 = pw[n], p1 = 1.f - p0;
  const unsigned short* y0 = Y + (size_t)(s0 < 0 ? 0 : s0) * DDIM;
  const unsigned short* y1 = Y + (size_t)(s1 < 0 ? 0 : s1) * DDIM;
  if (s0 < 0) p0 = 0.f;
  if (s1 < 0) p1 = 0.f;
  int t = threadIdx.x;
  float v0 = p0 * bf2f(y0[t])       + p1 * bf2f(y1[t]);
  float v1 = p0 * bf2f(y0[t + 256]) + p1 * bf2f(y1[t + 256]);
  float v2 = p0 * bf2f(y0[t + 512]) + p1 * bf2f(y1[t + 512]);
  float s = v0 + v1 + v2;
  float ss = v0 * v0 + v1 * v1 + v2 * v2;
  for (int o = 32; o > 0; o >>= 1) { s += __shfl_xor(s, o, 64); ss += __shfl_xor(ss, o, 64); }
  int wave = t >> 6, lane = t & 63;
  if (lane == 0) { red[wave] = s; red[4 + wave] = ss; }
  __syncthreads();
  s = red[0] + red[1] + red[2] + red[3];
  ss = red[4] + red[5] + red[6] + red[7];
  float mu = s * (1.f / DDIM);
  float var = ss * (1.f / DDIM) - mu * mu;
  float rs = rsqrtf(var + 1e-5f);
  float* row = out + (size_t)n * DDIM;
  row[t]       = (v0 - mu) * rs * lnw[t]       + lnb[t];
  row[t + 256] = (v1 - mu) * rs * lnw[t + 256] + lnb[t + 256];
  row[t + 512] = (v2 - mu) * rs * lnw[t + 512] + lnb[t + 512];
}

// sentinel fill: signals "workspace too small" via a distinctive absmax
__global__ void sentinel_kernel(float* __restrict__ out, int n) {
  int i = blockIdx.x * 256 + threadIdx.x;
  if (i < n) out[i] = 12345.0f;
}

// ---------------------------------------------------------------------------
extern "C" void kernel_launch(void* const* d_in, const int* in_sizes, int n_in,
                              void* d_out, int out_size, void* d_ws, size_t ws_size,
                              hipStream_t stream)
{
  const float* x   = (const float*)d_in[0];
  const float* wg  = (const float*)d_in[1];
  const float* w1  = (const float*)d_in[2];
  const float* b1  = (const float*)d_in[3];
  const float* w2  = (const float*)d_in[4];
  const float* b2  = (const float*)d_in[5];
  const float* lnw = (const float*)d_in[6];
  const float* lnb = (const float*)d_in[7];
  float* out = (float*)d_out;

  char* ws = (char*)d_ws;
  size_t off = 0;
  auto take = [&](size_t bytes) {
    char* p = ws + off; off += (bytes + 255) & ~(size_t)255; return p;
  };
  unsigned short* xb   = (unsigned short*)take((size_t)NTOK * DDIM * 2);        // 50.3 MB
  unsigned short* w1bt = (unsigned short*)take((size_t)NEXP * DDIM * HDIM * 2); // 37.7 MB
  unsigned short* w2bt = (unsigned short*)take((size_t)NEXP * DDIM * HDIM * 2); // 37.7 MB
  int*   tokidx = (int*)take((size_t)NEXP * CAP * 4);
  unsigned int* pair = (unsigned int*)take((size_t)NTOK * 4);
  float* pw   = (float*)take((size_t)NTOK * 4);
  int*   slotof = (int*)take((size_t)NTOK * 2 * 4);
  int*   cnt  = (int*)take(256);
  unsigned short* Ybuf = (unsigned short*)take((size_t)NEXP * CAP * DDIM * 2);  // 125.8 MB

  // Adaptive H-chunk: Mc token rows per expert (multiple of 256 for the
  // 256-row GEMM tiles), bounded by remaining workspace.
  size_t avail = (ws_size > off) ? (ws_size - off) : 0;
  long long cand = (long long)(avail / ((size_t)NEXP * HDIM * 2));  // rows/expert
  int Mc = (int)((cand / 256) * 256);
  if (Mc > CAP) Mc = CAP;
  if (Mc < 256) {   // cannot run at all — emit sentinel instead of crashing
    sentinel_kernel<<<(NTOK * DDIM + 255) / 256, 256, 0, stream>>>(out, NTOK * DDIM);
    return;
  }
  unsigned short* Hbuf = (unsigned short*)take((size_t)NEXP * Mc * HDIM * 2);

  router_assign<<<NTOK / 32, 256, 0, stream>>>(x, wg, xb, pair, pw);
  transpose_kernel<<<dim3(HDIM / 64, DDIM / 64, NEXP), 256, 0, stream>>>(w1, w1bt, DDIM, HDIM);
  transpose_kernel<<<dim3(DDIM / 64, HDIM / 64, NEXP), 256, 0, stream>>>(w2, w2bt, HDIM, DDIM);
  router_scatter<<<NEXP, 256, 0, stream>>>(pair, cnt, tokidx, slotof);

  for (int mbase = 0; mbase < CAP; mbase += Mc) {
    int rows = CAP - mbase; if (rows > Mc) rows = Mc;
    int mt = rows / 256;
    moe_gemm<0, DDIM, HDIM><<<(HDIM / 256) * mt * NEXP, 512, 0, stream>>>(
        xb, w1bt, b1, cnt, tokidx, Hbuf, mbase, Mc, mt);
    moe_gemm<1, HDIM, DDIM><<<(DDIM / 256) * mt * NEXP, 512, 0, stream>>>(
        Hbuf, w2bt, b2, cnt, tokidx, Ybuf, mbase, Mc, mt);
  }

  combine_ln<<<NTOK, 256, 0, stream>>>(Ybuf, slotof, pw, lnw, lnb, out);
}

// Round 4
// 1450.124 us; speedup vs baseline: 1.0741x; 1.0439x over previous
//
#include <hip/hip_runtime.h>
#include <math.h>

#define NTOK 32768
#define DDIM 768
#define HDIM 3072
#define NEXP 8
#define CAP  10240
#define NBLK 128            // NTOK/256 token blocks for count/scan/scatter

typedef short short8 __attribute__((ext_vector_type(8)));
typedef float f32x4 __attribute__((ext_vector_type(4)));

__device__ __forceinline__ unsigned short f2bf(float f) {
  unsigned u = __float_as_uint(f);
  u += 0x7FFFu + ((u >> 16) & 1u);   // round-to-nearest-even (finite inputs)
  return (unsigned short)(u >> 16);
}
__device__ __forceinline__ float bf2f(unsigned short h) {
  return __uint_as_float((unsigned)h << 16);
}

__device__ __forceinline__ void gload16(const void* g, void* l) {
  __builtin_amdgcn_global_load_lds(
      (const __attribute__((address_space(1))) void*)g,
      (__attribute__((address_space(3))) void*)l, 16, 0, 0);
}

// Fast exact-GELU: 0.5*v*(1+erf(v/sqrt2)), erf via A&S 7.1.26 (|err|<1.5e-7).
// Output is stored to bf16 (rel quantum ~4e-3) -> approximation error invisible.
__device__ __forceinline__ float gelu_fast(float v) {
  float z = v * 0.70710678118654752f;
  float a = fabsf(z);
  float t = 1.0f / (1.0f + 0.3275911f * a);
  float p = t * (0.254829592f +
           t * (-0.284496736f +
           t * (1.421413741f +
           t * (-1.453152027f +
           t * 1.061405429f))));
  float ex = __expf(-a * a);
  float er = 1.0f - p * ex;              // er in [0,1]
  er = copysignf(er, z);
  return 0.5f * v * (1.0f + er);
}

// ---------------------------------------------------------------------------
// Router phase 1: per-token top-2 + softmax -> pair/pw. Also x -> bf16.
// ---------------------------------------------------------------------------
__global__ __launch_bounds__(256) void router_assign(
    const float* __restrict__ x, const float* __restrict__ wg,
    unsigned short* __restrict__ xb,
    unsigned int* __restrict__ pair, float* __restrict__ pw)
{
  __shared__ float wt[NEXP][DDIM];       // transposed gate, 24 KB
  int t = threadIdx.x;
  for (int idx = t; idx < NEXP * DDIM; idx += 256) {
    int d = idx >> 3, e = idx & 7;       // wg is [768][8] row-major
    wt[e][d] = wg[idx];
  }
  __syncthreads();
  int wave = t >> 6, lane = t & 63;
  int n0 = blockIdx.x * 32 + wave * 8;
  for (int i = 0; i < 8; ++i) {
    int n = n0 + i;
    const float* xr = x + (size_t)n * DDIM;
    unsigned short* xbr = xb + (size_t)n * DDIM;
    float acc[NEXP];
#pragma unroll
    for (int e = 0; e < NEXP; ++e) acc[e] = 0.f;
#pragma unroll
    for (int c = 0; c < 3; ++c) {
      int d = c * 256 + lane * 4;
      float4 xv = *(const float4*)(xr + d);
      ushort4 pk;
      pk.x = f2bf(xv.x); pk.y = f2bf(xv.y); pk.z = f2bf(xv.z); pk.w = f2bf(xv.w);
      *(ushort4*)(xbr + d) = pk;
#pragma unroll
      for (int e = 0; e < NEXP; ++e) {
        float4 wv = *(const float4*)(&wt[e][d]);
        acc[e] += xv.x * wv.x + xv.y * wv.y + xv.z * wv.z + xv.w * wv.w;
      }
    }
#pragma unroll
    for (int e = 0; e < NEXP; ++e) {
      float v = acc[e];
      for (int o = 32; o > 0; o >>= 1) v += __shfl_xor(v, o, 64);
      acc[e] = v;
    }
    if (lane == 0) {
      int e1 = 0; float l1 = acc[0];
#pragma unroll
      for (int e = 1; e < NEXP; ++e) if (acc[e] > l1) { l1 = acc[e]; e1 = e; }
      int e2 = -1; float l2 = -INFINITY;
#pragma unroll
      for (int e = 0; e < NEXP; ++e) if (e != e1 && acc[e] > l2) { l2 = acc[e]; e2 = e; }
      float p1 = 1.f / (1.f + expf(l2 - l1));   // stable 2-way softmax
      pair[n] = (unsigned)e1 | ((unsigned)e2 << 8);
      pw[n] = p1;
    }
  }
}

// ---------------------------------------------------------------------------
// Parallel routing compaction, 3 phases (replaces the 8-block serial scatter):
//  count:  per 256-token block, per-expert counts (ballot-based)
//  scan:   exclusive prefix over blocks per expert (8 waves, 1 block)
//  scatter:each block writes its tokens at precomputed bases (token order kept)
// ---------------------------------------------------------------------------
__global__ __launch_bounds__(256) void moe_count(
    const unsigned int* __restrict__ pair, int* __restrict__ bcnt)
{
  __shared__ int c8[NEXP];
  int b = blockIdx.x, t = threadIdx.x, lane = t & 63;
  if (t < NEXP) c8[t] = 0;
  __syncthreads();
  unsigned p = pair[b * 256 + t];
  int e1 = p & 255, e2 = (p >> 8) & 255;
#pragma unroll
  for (int e = 0; e < NEXP; ++e) {
    int c = __popcll(__ballot(e1 == e)) + __popcll(__ballot(e2 == e));
    if (lane == 0 && c) atomicAdd(&c8[e], c);
  }
  __syncthreads();
  if (t < NEXP) bcnt[b * NEXP + t] = c8[t];
}

__global__ __launch_bounds__(512) void moe_scan(
    const int* __restrict__ bcnt, int* __restrict__ bbase, int* __restrict__ cnt)
{
  int t = threadIdx.x, w = t >> 6, lane = t & 63;   // wave w = expert w
  if (lane == 0) {
    int run = 0;
    for (int b = 0; b < NBLK; ++b) { bbase[b * NEXP + w] = run; run += bcnt[b * NEXP + w]; }
    cnt[w] = (run < CAP) ? run : CAP;
  }
}

__global__ __launch_bounds__(256) void moe_scatter(
    const unsigned int* __restrict__ pair, const int* __restrict__ bbase,
    int* __restrict__ tokidx, int* __restrict__ slotof)
{
  __shared__ int wcnt[4][NEXP];
  __shared__ int woffs[4][NEXP];
  int b = blockIdx.x, t = threadIdx.x, wave = t >> 6, lane = t & 63;
  int n = b * 256 + t;
  unsigned p = pair[n];
  int e1 = p & 255, e2 = (p >> 8) & 255;
  unsigned long long below = (lane == 63) ? 0x7FFFFFFFFFFFFFFFull
                                          : ((1ull << lane) - 1ull);
  int pre1 = 0, pre2 = 0;
#pragma unroll
  for (int e = 0; e < NEXP; ++e) {
    unsigned long long b1 = __ballot(e1 == e);
    unsigned long long b2 = __ballot(e2 == e);
    if (e1 == e) pre1 = __popcll(b1 & below);
    if (e2 == e) pre2 = __popcll(b1) + __popcll(b2 & below);
    if (lane == 0) wcnt[wave][e] = __popcll(b1) + __popcll(b2);
  }
  __syncthreads();
  if (t < 4 * NEXP) {
    int w = t >> 3, e = t & 7;
    int s = 0;
    for (int w2 = 0; w2 < w; ++w2) s += wcnt[w2][e];
    woffs[w][e] = s;
  }
  __syncthreads();
  int g1 = bbase[b * NEXP + e1] + woffs[wave][e1] + pre1;
  int g2 = bbase[b * NEXP + e2] + woffs[wave][e2] + pre2;
  if (g1 < CAP) { tokidx[e1 * CAP + g1] = n; slotof[2 * n] = e1 * CAP + g1; }
  else slotof[2 * n] = -1;
  if (g2 < CAP) { tokidx[e2 * CAP + g2] = n; slotof[2 * n + 1] = e2 * CAP + g2; }
  else slotof[2 * n + 1] = -1;
}

// ---------------------------------------------------------------------------
// Both weight transposes in ONE launch: src [E][R][C] -> dst [E][C][R] (bf16)
// half 0: w1 (R=768,C=3072,576 tiles/e)  half 1: w2 (R=3072,C=768)
// ---------------------------------------------------------------------------
__global__ __launch_bounds__(256) void transpose_all(
    const float* __restrict__ w1, const float* __restrict__ w2,
    unsigned short* __restrict__ d1, unsigned short* __restrict__ d2)
{
  __shared__ float tile[64][65];
  int bid = blockIdx.x;
  int half = bid / (576 * NEXP);
  int r = bid - half * 576 * NEXP;
  int e = r / 576, rr = r - e * 576;
  const float* src; unsigned short* dst; int R, C, cx, cy;
  if (half == 0) { src = w1; dst = d1; R = DDIM; C = HDIM; cx = rr % 48; cy = rr / 48; }
  else           { src = w2; dst = d2; R = HDIM; C = DDIM; cx = rr % 12; cy = rr / 12; }
  const float* s = src + (size_t)e * R * C;
  unsigned short* d = dst + (size_t)e * R * C;
  int c0 = cx * 64, r0 = cy * 64;
  int tc = threadIdx.x & 63, tg = threadIdx.x >> 6;
#pragma unroll
  for (int q = tg; q < 64; q += 4)
    tile[q][tc] = s[(size_t)(r0 + q) * C + c0 + tc];
  __syncthreads();
#pragma unroll
  for (int q = tg; q < 64; q += 4)
    d[(size_t)(c0 + q) * R + r0 + tc] = f2bf(tile[tc][q]);
}

// ---------------------------------------------------------------------------
// Grouped GEMM, 256x256-tile 8-phase schedule (unchanged from r3).
// vmcnt(8) at every odd phase = 4 half-tiles in flight; T2 swizzle
// (SQ_LDS_BANK_CONFLICT measured 0); T1 bijective XCD-chunk remap
// (FETCH measured at compulsory minimum).
// EPI=0: Obuf[e*Mc + row] = gelu(gather(xb) @ w1bt^T + b1)        (bf16)
// EPI=1: Obuf[e*CAP + gm] = Hbuf @ w2bt^T + b2  (bf16, un-weighted)
// ---------------------------------------------------------------------------
template<int EPI, int KK, int NN>
__global__ __launch_bounds__(512, 2) void moe_gemm(
    const unsigned short* __restrict__ A,
    const unsigned short* __restrict__ Bt,
    const float* __restrict__ bias,
    const int* __restrict__ cnt,
    const int* __restrict__ tokidx,
    unsigned short* __restrict__ Obuf,
    int mbase, int Mc, int mt)
{
  constexpr int KT = KK / 64;     // K-tiles of 64
  constexpr int NI = KT / 2;      // 2 K-tiles per iteration (NI >= 2)
  constexpr int GX = NN / 256;    // N-tiles (compile-time)

  // ---- T1: bijective XCD-chunk remap of flattened block id ----
  int nwg = gridDim.x;
  int orig = blockIdx.x;
  int q = nwg >> 3, r = nwg & 7;
  int xcd = orig & 7, loc = orig >> 3;
  int base = (xcd < r) ? xcd * (q + 1) : r * (q + 1) + (xcd - r) * q;
  int wg = base + loc;
  int per_e = GX * mt;
  int e = wg / per_e;
  int rem = wg - e * per_e;
  int by = rem / GX;
  int bx = rem - by * GX;

  int M = cnt[e]; if (M > CAP) M = CAP;
  int ly0 = by * 256;                   // local row base within chunk
  int gm0 = mbase + ly0;                // global slot base
  if (gm0 >= M) return;
  int n0 = bx * 256;
  int t = threadIdx.x, wave = t >> 6, lane = t & 63;
  int wr = wave >> 2, wc = wave & 3;    // 2M x 4N wave grid
  int lane15 = lane & 15, quad = lane >> 4;

  __shared__ __align__(16) char smem[131072];

  // ---- staging: each thread owns 2 of the 1024 16B-chunks per half-tile ----
  int ci0 = wave * 128 + lane;
  int ci1 = ci0 + 64;
  int r0 = ci0 >> 2, r1 = ci1 >> 2;     // tile row 0..255
  int c0 = (ci0 & 3) ^ ((r0 >> 1) & 3); // pre-swizzled source chunk in K-half
  int c1 = (ci1 & 3) ^ ((r1 >> 1) & 3);
  const unsigned short *aB0, *aB1, *bB0, *bB1;
  if (EPI == 0) {
    int g0 = gm0 + r0; if (g0 >= M) g0 = M - 1;   // clamp to a valid slot
    int g1 = gm0 + r1; if (g1 >= M) g1 = M - 1;
    aB0 = A + (size_t)tokidx[e * CAP + g0] * KK + c0 * 8;
    aB1 = A + (size_t)tokidx[e * CAP + g1] * KK + c1 * 8;
  } else {
    aB0 = A + ((size_t)e * Mc + ly0 + r0) * KK + c0 * 8;
    aB1 = A + ((size_t)e * Mc + ly0 + r1) * KK + c1 * 8;
  }
  bB0 = Bt + ((size_t)e * NN + n0 + r0) * KK + c0 * 8;
  bB1 = Bt + ((size_t)e * NN + n0 + r1) * KK + c1 * 8;

  // dest: smem + buf*65536 + ab*32768 + kh*16384 + wave*2048 (+1024), +lane*16 by HW
#define STAGE_A(buf, kh, kt_) do { \
    gload16(aB0 + (kt_) * 64 + (kh) * 32, smem + (buf) * 65536 + (kh) * 16384 + wave * 2048); \
    gload16(aB1 + (kt_) * 64 + (kh) * 32, smem + (buf) * 65536 + (kh) * 16384 + wave * 2048 + 1024); \
  } while (0)
#define STAGE_B(buf, kh, kt_) do { \
    gload16(bB0 + (kt_) * 64 + (kh) * 32, smem + (buf) * 65536 + 32768 + (kh) * 16384 + wave * 2048); \
    gload16(bB1 + (kt_) * 64 + (kh) * 32, smem + (buf) * 65536 + 32768 + (kh) * 16384 + wave * 2048 + 1024); \
  } while (0)

  // ---- ds_read fragment offsets (swizzled) ----
  int aoffb[8], boffb[4];
#pragma unroll
  for (int m = 0; m < 8; ++m) {
    int row = wr * 128 + m * 16 + lane15;
    aoffb[m] = row * 64 + ((quad ^ ((row >> 1) & 3)) * 16);
  }
#pragma unroll
  for (int n = 0; n < 4; ++n) {
    int row = wc * 64 + n * 16 + lane15;
    boffb[n] = 32768 + row * 64 + ((quad ^ ((row >> 1) & 3)) * 16);
  }

  f32x4 acc[8][4];
#pragma unroll
  for (int mf = 0; mf < 8; ++mf)
#pragma unroll
    for (int n = 0; n < 4; ++n)
#pragma unroll
      for (int r2 = 0; r2 < 4; ++r2) acc[mf][n][r2] = 0.f;

  short8 af[4], bf[4];

#define BAR()  __builtin_amdgcn_s_barrier()
#define WVM8() asm volatile("s_waitcnt vmcnt(8)" ::: "memory")
#define WVM4() asm volatile("s_waitcnt vmcnt(4)" ::: "memory")
#define WVM0() asm volatile("s_waitcnt vmcnt(0)" ::: "memory")
#define RD_B(buf, ks) do { \
    _Pragma("unroll") \
    for (int n = 0; n < 4; ++n) \
      bf[n] = *(const short8*)(smem + (buf) * 65536 + (ks) * 16384 + boffb[n]); \
  } while (0)
#define RD_A(buf, ks, mh) do { \
    _Pragma("unroll") \
    for (int m = 0; m < 4; ++m) \
      af[m] = *(const short8*)(smem + (buf) * 65536 + (ks) * 16384 + aoffb[(mh) * 4 + m]); \
  } while (0)
#define MM(mh) do { \
    __builtin_amdgcn_s_setprio(1); \
    _Pragma("unroll") \
    for (int m = 0; m < 4; ++m) \
      _Pragma("unroll") \
      for (int n = 0; n < 4; ++n) \
        acc[(mh) * 4 + m][n] = __builtin_amdgcn_mfma_f32_16x16x32_bf16( \
            af[m], bf[n], acc[(mh) * 4 + m][n], 0, 0, 0); \
    __builtin_amdgcn_s_setprio(0); \
  } while (0)

  // ---- prologue: buf0 <- tile0 (all 4 halves), buf1.kh0 <- tile1 ----
  STAGE_A(0, 0, 0); STAGE_B(0, 0, 0);
  STAGE_A(0, 1, 0); STAGE_B(0, 1, 0);
  STAGE_A(1, 0, 1); STAGE_B(1, 0, 1);
  WVM8();                // buf0.kh0 landed; 8 in flight (buf0.kh1, buf1.kh0)
  BAR();

#pragma unroll 1
  for (int it = 0; it < NI - 1; ++it) {
    int kt = 2 * it;
    // ph0
    RD_B(0, 0); RD_A(0, 0, 0); STAGE_A(1, 1, kt + 1);
    BAR(); MM(0); BAR();
    // ph1
    RD_A(0, 0, 1); STAGE_B(1, 1, kt + 1);
    BAR(); MM(1); WVM8(); BAR();     // buf0.kh1 landed (ph2 reads)
    // ph2
    RD_B(0, 1); RD_A(0, 1, 0); STAGE_A(0, 0, kt + 2);
    BAR(); MM(0); BAR();
    // ph3
    RD_A(0, 1, 1); STAGE_B(0, 0, kt + 2);
    BAR(); MM(1); WVM8(); BAR();     // buf1.kh0 landed (ph4 reads)
    // ph4
    RD_B(1, 0); RD_A(1, 0, 0); STAGE_A(0, 1, kt + 2);
    BAR(); MM(0); BAR();
    // ph5
    RD_A(1, 0, 1); STAGE_B(0, 1, kt + 2);
    BAR(); MM(1); WVM8(); BAR();     // buf1.kh1 landed (ph6 reads)
    // ph6
    RD_B(1, 1); RD_A(1, 1, 0); STAGE_A(1, 0, kt + 3);
    BAR(); MM(0); BAR();
    // ph7
    RD_A(1, 1, 1); STAGE_B(1, 0, kt + 3);
    BAR(); MM(1); WVM8(); BAR();     // buf0.kh0 landed (next ph0 reads)
  }

  // ---- peeled tail (tiles KT-2 / KT-1): stage only buf1.kh1; drain 8->4->0 ----
  {
    constexpr int kt = 2 * (NI - 1);
    RD_B(0, 0); RD_A(0, 0, 0); STAGE_A(1, 1, kt + 1);
    BAR(); MM(0); BAR();
    RD_A(0, 0, 1); STAGE_B(1, 1, kt + 1);
    BAR(); MM(1); WVM8(); BAR();     // buf0.kh1 landed
    RD_B(0, 1); RD_A(0, 1, 0);
    BAR(); MM(0); BAR();
    RD_A(0, 1, 1);
    BAR(); MM(1); WVM4(); BAR();     // buf1.kh0 landed
    RD_B(1, 0); RD_A(1, 0, 0);
    BAR(); MM(0); BAR();
    RD_A(1, 0, 1);
    BAR(); MM(1); WVM0(); BAR();     // buf1.kh1 landed
    RD_B(1, 1); RD_A(1, 1, 0);
    BAR(); MM(0); BAR();
    RD_A(1, 1, 1);
    BAR(); MM(1);
  }

  // epilogue: C/D layout col=lane&15, row=quad*4+reg  [m89-verified]
  if (EPI == 0) {
#pragma unroll
    for (int n = 0; n < 4; ++n) {
      int col = n0 + wc * 64 + n * 16 + lane15;
      float bcol = bias[e * NN + col];
#pragma unroll
      for (int mf = 0; mf < 8; ++mf) {
        int rowb = ly0 + wr * 128 + mf * 16 + quad * 4;   // local row
#pragma unroll
        for (int r2 = 0; r2 < 4; ++r2) {
          float v = gelu_fast(acc[mf][n][r2] + bcol);
          Obuf[((size_t)e * Mc + rowb + r2) * NN + col] = f2bf(v);
        }
      }
    }
  } else {
    float bc[4];
#pragma unroll
    for (int n = 0; n < 4; ++n)
      bc[n] = bias[e * NN + n0 + wc * 64 + n * 16 + lane15];
#pragma unroll
    for (int mf = 0; mf < 8; ++mf) {
      int gmb = gm0 + wr * 128 + mf * 16 + quad * 4;      // global slot
#pragma unroll
      for (int r2 = 0; r2 < 4; ++r2) {
        int gm = gmb + r2;
        if (gm < M) {
          unsigned short* yrow = Obuf + ((size_t)e * CAP + gm) * NN;
#pragma unroll
          for (int n = 0; n < 4; ++n) {
            int col = n0 + wc * 64 + n * 16 + lane15;
            yrow[col] = f2bf(acc[mf][n][r2] + bc[n]);
          }
        }
      }
    }
  }
#undef STAGE_A
#undef STAGE_B
#undef BAR
#undef WVM8
#undef WVM4
#undef WVM0
#undef RD_B
#undef RD_A
#undef MM
}

// ---------------------------------------------------------------------------
// Fused combine + LayerNorm, ONE WAVE PER TOKEN, vectorized ushort4 loads.
// 12 bf16/lane per row (3 x ushort4), wave-only reduction, float4 stores.
// ---------------------------------------------------------------------------
__global__ __launch_bounds__(512) void combine_ln(
    const unsigned short* __restrict__ Y, const int* __restrict__ slotof,
    const float* __restrict__ pw,
    const float* __restrict__ lnw, const float* __restrict__ lnb,
    float* __restrict__ out)
{
  int w = threadIdx.x >> 6, lane = threadIdx.x & 63;
  int n = blockIdx.x * 8 + w;
  int s0 = slotof[2 * n], s1 = slotof[2 * n + 1];
  float p0 = pw[n], p1 = 1.f - p0;
  const unsigned short* y0 = Y + (size_t)(s0 < 0 ? 0 : s0) * DDIM;
  const unsigned short* y1 = Y + (size_t)(s1 < 0 ? 0 : s1) * DDIM;
  if (s0 < 0) p0 = 0.f;
  if (s1 < 0) p1 = 0.f;
  float v[12];
  float s = 0.f, ss = 0.f;
#pragma unroll
  for (int c = 0; c < 3; ++c) {
    int d = c * 256 + lane * 4;
    ushort4 a = *(const ushort4*)(y0 + d);
    ushort4 b = *(const ushort4*)(y1 + d);
    float4 fa = { bf2f(a.x), bf2f(a.y), bf2f(a.z), bf2f(a.w) };
    float4 fb = { bf2f(b.x), bf2f(b.y), bf2f(b.z), bf2f(b.w) };
    v[c * 4 + 0] = p0 * fa.x + p1 * fb.x;
    v[c * 4 + 1] = p0 * fa.y + p1 * fb.y;
    v[c * 4 + 2] = p0 * fa.z + p1 * fb.z;
    v[c * 4 + 3] = p0 * fa.w + p1 * fb.w;
#pragma unroll
    for (int j = 0; j < 4; ++j) { s += v[c * 4 + j]; ss += v[c * 4 + j] * v[c * 4 + j]; }
  }
  for (int o = 32; o > 0; o >>= 1) { s += __shfl_xor(s, o, 64); ss += __shfl_xor(ss, o, 64); }
  float mu = s * (1.f / DDIM);
  float var = ss * (1.f / DDIM) - mu * mu;
  float rs = rsqrtf(var + 1e-5f);
  float* row = out + (size_t)n * DDIM;
#pragma unroll
  for (int c = 0; c < 3; ++c) {
    int d = c * 256 + lane * 4;
    float4 lw = *(const float4*)(lnw + d);
    float4 lb = *(const float4*)(lnb + d);
    float4 o;
    o.x = (v[c * 4 + 0] - mu) * rs * lw.x + lb.x;
    o.y = (v[c * 4 + 1] - mu) * rs * lw.y + lb.y;
    o.z = (v[c * 4 + 2] - mu) * rs * lw.z + lb.z;
    o.w = (v[c * 4 + 3] - mu) * rs * lw.w + lb.w;
    *(float4*)(row + d) = o;
  }
}

// sentinel fill: signals "workspace too small" via a distinctive absmax
__global__ void sentinel_kernel(float* __restrict__ out, int n) {
  int i = blockIdx.x * 256 + threadIdx.x;
  if (i < n) out[i] = 12345.0f;
}

// ---------------------------------------------------------------------------
extern "C" void kernel_launch(void* const* d_in, const int* in_sizes, int n_in,
                              void* d_out, int out_size, void* d_ws, size_t ws_size,
                              hipStream_t stream)
{
  const float* x   = (const float*)d_in[0];
  const float* wg  = (const float*)d_in[1];
  const float* w1  = (const float*)d_in[2];
  const float* b1  = (const float*)d_in[3];
  const float* w2  = (const float*)d_in[4];
  const float* b2  = (const float*)d_in[5];
  const float* lnw = (const float*)d_in[6];
  const float* lnb = (const float*)d_in[7];
  float* out = (float*)d_out;

  char* ws = (char*)d_ws;
  size_t off = 0;
  auto take = [&](size_t bytes) {
    char* p = ws + off; off += (bytes + 255) & ~(size_t)255; return p;
  };
  unsigned short* xb   = (unsigned short*)take((size_t)NTOK * DDIM * 2);        // 50.3 MB
  unsigned short* w1bt = (unsigned short*)take((size_t)NEXP * DDIM * HDIM * 2); // 37.7 MB
  unsigned short* w2bt = (unsigned short*)take((size_t)NEXP * DDIM * HDIM * 2); // 37.7 MB
  int*   tokidx = (int*)take((size_t)NEXP * CAP * 4);
  unsigned int* pair = (unsigned int*)take((size_t)NTOK * 4);
  float* pw   = (float*)take((size_t)NTOK * 4);
  int*   slotof = (int*)take((size_t)NTOK * 2 * 4);
  int*   cnt  = (int*)take(256);
  int*   bcnt  = (int*)take((size_t)NBLK * NEXP * 4);
  int*   bbase = (int*)take((size_t)NBLK * NEXP * 4);
  unsigned short* Ybuf = (unsigned short*)take((size_t)NEXP * CAP * DDIM * 2);  // 125.8 MB

  // Adaptive H-chunk: Mc token rows per expert (multiple of 256 for the
  // 256-row GEMM tiles), bounded by remaining workspace.
  size_t avail = (ws_size > off) ? (ws_size - off) : 0;
  long long cand = (long long)(avail / ((size_t)NEXP * HDIM * 2));  // rows/expert
  int Mc = (int)((cand / 256) * 256);
  if (Mc > CAP) Mc = CAP;
  if (Mc < 256) {   // cannot run at all — emit sentinel instead of crashing
    sentinel_kernel<<<(NTOK * DDIM + 255) / 256, 256, 0, stream>>>(out, NTOK * DDIM);
    return;
  }
  unsigned short* Hbuf = (unsigned short*)take((size_t)NEXP * Mc * HDIM * 2);

  router_assign<<<NTOK / 32, 256, 0, stream>>>(x, wg, xb, pair, pw);
  transpose_all<<<576 * NEXP * 2, 256, 0, stream>>>(w1, w2, w1bt, w2bt);
  moe_count<<<NBLK, 256, 0, stream>>>(pair, bcnt);
  moe_scan<<<1, 512, 0, stream>>>(bcnt, bbase, cnt);
  moe_scatter<<<NBLK, 256, 0, stream>>>(pair, bbase, tokidx, slotof);

  for (int mbase = 0; mbase < CAP; mbase += Mc) {
    int rows = CAP - mbase; if (rows > Mc) rows = Mc;
    int mt = rows / 256;
    moe_gemm<0, DDIM, HDIM><<<(HDIM / 256) * mt * NEXP, 512, 0, stream>>>(
        xb, w1bt, b1, cnt, tokidx, Hbuf, mbase, Mc, mt);
    moe_gemm<1, HDIM, DDIM><<<(DDIM / 256) * mt * NEXP, 512, 0, stream>>>(
        Hbuf, w2bt, b2, cnt, tokidx, Ybuf, mbase, Mc, mt);
  }

  combine_ln<<<NTOK / 8, 512, 0, stream>>>(Ybuf, slotof, pw, lnw, lnb, out);
}